// Round 5
// baseline (135.244 us; speedup 1.0000x reference)
//
#include <hip/hip_runtime.h>

#define PI_D 3.14159265358979323846

typedef __attribute__((ext_vector_type(8))) short bf16x8;
typedef __attribute__((ext_vector_type(4))) float f32x4;

static __device__ inline f32x4 mfma16(bf16x8 a, bf16x8 b, f32x4 c) {
    return __builtin_amdgcn_mfma_f32_16x16x32_bf16(a, b, c, 0, 0, 0);
}

// f32 -> bf16 RNE via native __bf16 cast: clang emits v_cvt_pk_bf16_f32 for pairs
// (bit-identical to the old integer RNE for all finite values).
static __device__ inline unsigned short f2bf(float f) {
    union { __bf16 h; unsigned short u; } v;
    v.h = (__bf16)f;
    return v.u;
}
static __device__ inline float bf2f(unsigned short h) {
    union { unsigned u; float f; } v; v.u = ((unsigned)h) << 16;
    return v.f;
}

// load 8 consecutive f32 from global, convert to bf16x8 (RNE, hw cvt_pk)
static __device__ inline bf16x8 ld_cvt8(const float* __restrict__ p) {
    float4 v0 = *(const float4*)p;
    float4 v1 = *(const float4*)(p + 4);
    bf16x8 r;
    r[0] = (short)f2bf(v0.x); r[1] = (short)f2bf(v0.y);
    r[2] = (short)f2bf(v0.z); r[3] = (short)f2bf(v0.w);
    r[4] = (short)f2bf(v1.x); r[5] = (short)f2bf(v1.y);
    r[6] = (short)f2bf(v1.z); r[7] = (short)f2bf(v1.w);
    return r;
}

// ---- ws float layout ----------------------------------------------------------------
#define OFF_TAB 0                         // 32768 bf16 = 16384 floats (only A3/E4 used)
#define OFF_XFR  (16384 + 1048576)        // 1024 bids x 512 modes f32 (re)
#define OFF_XFI  (OFF_XFR + 524288)       // (im)

// table offsets in u16 units within OFF_TAB
#define TAB_A3 20480    // [128 x][64 k=c*32+m]
#define TAB_E4 28672    // [128 y][32 k=p*16+ky]

// ---------------- forward + prep: kernel 1 --------------------------------------------
// Per block (b,i): forward transform of one image. Twiddles: 128 distinct angles ->
// bf16 lookup tables built once; E1 staged as an 8KB LDS fragment table (reused by all
// 4 waves); A2 elements thread-unique, generated from bc/bs at ~4 ops each.
// Blocks 0/1 additionally emit the A3/E4 global tables for k_im.
__global__ __launch_bounds__(256) void k_f(const float* __restrict__ x, float* ws) {
    __shared__ float c128[128], s128[128];
    __shared__ unsigned short cb[128], sb[128], bc[128], bs[128];
    __shared__ __align__(16) unsigned short E1l[32 * 136];   // [n=c*16+ky][w]
    __shared__ __align__(16) unsigned short Yl[16 * 264];    // Y: [ky][k=c*128+x]
    int t = threadIdx.x, bid = blockIdx.x;
    const float W128 = (float)(2.0 * PI_D / 128.0);
    const float inv128 = 1.f / 128.f;
    if (t < 128) {
        float th = t * W128, c = cosf(th), s = sinf(th);
        c128[t] = c; s128[t] = s;
        cb[t] = f2bf(c * inv128);
        sb[t] = f2bf(-s * inv128);
        bc[t] = f2bf(c);
        bs[t] = f2bf(s);
    }
    __syncthreads();

    // build E1l fragment table from cb/sb (each entry reused by 4 waves)
    for (int e = t; e < 4096; e += 256) {
        int row = e >> 7, col = e & 127;
        int ky = row & 15, c = row >> 4;
        int a = (col * ky) & 127;
        E1l[row * 136 + col] = c ? sb[a] : cb[a];
    }

    // side duty: blocks 0/1 emit the inverse-DFT tables for k_im (bit-identical math)
    unsigned short* tabw = (unsigned short*)(ws + OFF_TAB);
    if (bid == 0) {
        for (int idx = t; idx < 8192; idx += 256) {          // A3: inverse x-DFT
            int xx = idx >> 6, k = idx & 63, c = k >> 5, m = k & 31;
            int kx = (m < 16) ? m : 96 + m;
            int a = (xx * kx) & 127;
            float val = (c == 0) ? c128[a] : -s128[a];
            tabw[TAB_A3 + idx] = f2bf(val);
        }
    } else if (bid == 1) {
        for (int idx = t; idx < 4096; idx += 256) {          // E4t: inverse y-DFT
            int y = idx >> 5, k = idx & 31, p = k >> 4, ky = k & 15;
            int a = (y * ky) & 127;
            float sc = (ky == 0 ? 1.f : 2.f) / 128.f;
            float val = (p == 0) ? sc * c128[a] : -sc * s128[a];
            tabw[TAB_E4 + idx] = f2bf(val);
        }
    }
    __syncthreads();

    int lid = t & 15, q = (t >> 4) & 3, w = t >> 6;
    const float* xim = x + (size_t)bid * 16384;

    // F1: C[x][(c,ky)] = sum_w X[x][w] E1t[(c,ky)][w];  M=128 N=32 K=128
    f32x4 acc[2][2] = {};
#pragma unroll
    for (int ks = 0; ks < 4; ++ks) {
        bf16x8 a0 = ld_cvt8(xim + (32 * w + lid) * 128 + ks * 32 + q * 8);
        bf16x8 a1 = ld_cvt8(xim + (32 * w + 16 + lid) * 128 + ks * 32 + q * 8);
        bf16x8 b0 = *(const bf16x8*)&E1l[lid * 136 + ks * 32 + q * 8];
        bf16x8 b1 = *(const bf16x8*)&E1l[(16 + lid) * 136 + ks * 32 + q * 8];
        acc[0][0] = mfma16(a0, b0, acc[0][0]);
        acc[0][1] = mfma16(a0, b1, acc[0][1]);
        acc[1][0] = mfma16(a1, b0, acc[1][0]);
        acc[1][1] = mfma16(a1, b1, acc[1][1]);
    }
    // epilogue: Y -> Yl[ky][c*128+x] bf16
#pragma unroll
    for (int mt = 0; mt < 2; ++mt)
#pragma unroll
        for (int nt = 0; nt < 2; ++nt) {
            ushort4 h;
            h.x = f2bf(acc[mt][nt][0]); h.y = f2bf(acc[mt][nt][1]);
            h.z = f2bf(acc[mt][nt][2]); h.w = f2bf(acc[mt][nt][3]);
            *(ushort4*)&Yl[lid * 264 + nt * 128 + 32 * w + mt * 16 + q * 4] = h;
        }
    __syncthreads();

    // F2: C[(p,m)][ky] = sum_k A2[(p,m)][k] Yl[ky][k];  M=64 N=16 K=256
    f32x4 acc2 = {};
    {
        int row = 16 * w + lid, p = row >> 5, m = row & 31;
        int kx = (m < 16) ? m : 96 + m;
#pragma unroll
        for (int ks = 0; ks < 8; ++ks) {
            const bool cc = (ks >= 4);         // c = k>>7, compile-time per ks
            bf16x8 a;
#pragma unroll
            for (int j = 0; j < 8; ++j) {
                int xx = (ks * 32 + q * 8 + j) & 127;
                int ang = (xx * kx) & 127;
                unsigned short v;
                if (p == 0) v = cc ? bs[ang] : bc[ang];                      // er / -ei
                else        v = cc ? bc[ang] : (unsigned short)(bs[ang] ^ 0x8000u); // er / ei
                a[j] = (short)v;
            }
            bf16x8 b = *(const bf16x8*)&Yl[lid * 264 + ks * 32 + q * 8];
            acc2 = mfma16(a, b, acc2);
        }
    }
    int p = w >> 1, mb = (w & 1) * 16;
    float* xfp = ws + (p ? OFF_XFI : OFF_XFR) + (size_t)bid * 512;
#pragma unroll
    for (int r = 0; r < 4; ++r)
        xfp[(mb + q * 4 + r) * 16 + lid] = acc2[r];
}

// ---------------- fused mix + inverse: block (b, o-pair) -> out[b,2o,:,:] -------------
// o-pair register blocking (grid 512 -> 2 blocks/CU resident, 2x the TLP of the o-quad
// version, still 2x xf reuse). Weights read DIRECTLY from wr/wi (relayout removed;
// identical FMA order -> bit-exact). Split-bf16 I1/I2 as before.
__global__ __launch_bounds__(256) void k_im(const float* __restrict__ ws,
                                            const float* __restrict__ wr,
                                            const float* __restrict__ wi,
                                            float* __restrict__ out) {
    __shared__ __align__(16) unsigned short Zlh[128 * 40];   // [x][k=p*16+ky] hi
    __shared__ __align__(16) unsigned short Zll[128 * 40];   // lo residual
    __shared__ __align__(16) unsigned short Blh[32 * 72];    // [(p,ky)][k=c*32+m] hi
    __shared__ __align__(16) unsigned short Bll[32 * 72];    // lo residual
    __shared__ float2 zm[2][512];
    int t = threadIdx.x, bid = blockIdx.x;                   // b*16 + o-pair
    int b = bid >> 4, o0 = (bid & 15) * 2;
    const unsigned short* tab = (const unsigned short*)(ws + OFF_TAB);

    // ---- channel mix, f32: zm[oo][mode] = sum_i xf[b,i,mode] * w[o0+oo,i,mode]
    {
        const float* xfr = ws + OFF_XFR + (size_t)(b * 32) * 512 + 2 * t;
        const float* xfi = ws + OFF_XFI + (size_t)(b * 32) * 512 + 2 * t;
        float ar[2][2] = {}, ai[2][2] = {};
#pragma unroll 4
        for (int i = 0; i < 32; ++i) {
            const float2 xr2 = *(const float2*)(xfr + (size_t)i * 512);
            const float2 xi2 = *(const float2*)(xfi + (size_t)i * 512);
#pragma unroll
            for (int oo = 0; oo < 2; ++oo) {
                const float2 wr2 = *(const float2*)(wr + (size_t)(i * 32 + o0 + oo) * 512 + 2 * t);
                const float2 wi2 = *(const float2*)(wi + (size_t)(i * 32 + o0 + oo) * 512 + 2 * t);
                ar[oo][0] = fmaf(xr2.x, wr2.x, fmaf(-xi2.x, wi2.x, ar[oo][0]));
                ai[oo][0] = fmaf(xr2.x, wi2.x, fmaf( xi2.x, wr2.x, ai[oo][0]));
                ar[oo][1] = fmaf(xr2.y, wr2.y, fmaf(-xi2.y, wi2.y, ar[oo][1]));
                ai[oo][1] = fmaf(xr2.y, wi2.y, fmaf( xi2.y, wr2.y, ai[oo][1]));
            }
        }
#pragma unroll
        for (int oo = 0; oo < 2; ++oo) {
            zm[oo][2 * t]     = make_float2(ar[oo][0], ai[oo][0]);
            zm[oo][2 * t + 1] = make_float2(ar[oo][1], ai[oo][1]);
        }
    }

    int lid = t & 15, q = (t >> 4) & 3, w = t >> 6;

    for (int oo = 0; oo < 2; ++oo) {
        __syncthreads();   // zm ready / previous I1-read of Blh done

        // build Blh/Bll from zm[oo] (complex-as-real with sign trick; hi + residual-lo)
        {
            int n = t >> 3, k0 = (t & 7) * 8;
            int p = n >> 4, ky = n & 15;
            unsigned short hh[8], hl[8];
#pragma unroll
            for (int j = 0; j < 8; ++j) {
                int k = k0 + j, c = k >> 5, m = k & 31;
                float2 v = zm[oo][m * 16 + ky];
                float val = (p == 0) ? (c == 0 ? v.x : v.y) : (c == 0 ? v.y : -v.x);
                unsigned short vh = f2bf(val);
                hh[j] = vh;
                hl[j] = f2bf(val - bf2f(vh));
            }
            ushort4 a, bb;
            a.x = hh[0]; a.y = hh[1]; a.z = hh[2]; a.w = hh[3];
            bb.x = hh[4]; bb.y = hh[5]; bb.z = hh[6]; bb.w = hh[7];
            *(ushort4*)&Blh[n * 72 + k0]     = a;
            *(ushort4*)&Blh[n * 72 + k0 + 4] = bb;
            a.x = hl[0]; a.y = hl[1]; a.z = hl[2]; a.w = hl[3];
            bb.x = hl[4]; bb.y = hl[5]; bb.z = hl[6]; bb.w = hl[7];
            *(ushort4*)&Bll[n * 72 + k0]     = a;
            *(ushort4*)&Bll[n * 72 + k0 + 4] = bb;
        }
        __syncthreads();

        // I1: Z[x][(p,ky)] = sum_k A3[x][k] (Bh+Bl)[(p,ky)][k];  M=128 N=32 K=64
        f32x4 acc[2][2] = {};
#pragma unroll
        for (int ks = 0; ks < 2; ++ks) {
            bf16x8 a0  = *(const bf16x8*)&tab[TAB_A3 + (32 * w + lid) * 64 + ks * 32 + q * 8];
            bf16x8 a1  = *(const bf16x8*)&tab[TAB_A3 + (32 * w + 16 + lid) * 64 + ks * 32 + q * 8];
            bf16x8 bh0 = *(const bf16x8*)&Blh[lid * 72 + ks * 32 + q * 8];
            bf16x8 bh1 = *(const bf16x8*)&Blh[(16 + lid) * 72 + ks * 32 + q * 8];
            bf16x8 bl0 = *(const bf16x8*)&Bll[lid * 72 + ks * 32 + q * 8];
            bf16x8 bl1 = *(const bf16x8*)&Bll[(16 + lid) * 72 + ks * 32 + q * 8];
            acc[0][0] = mfma16(a0, bl0, acc[0][0]);
            acc[0][0] = mfma16(a0, bh0, acc[0][0]);
            acc[0][1] = mfma16(a0, bl1, acc[0][1]);
            acc[0][1] = mfma16(a0, bh1, acc[0][1]);
            acc[1][0] = mfma16(a1, bl0, acc[1][0]);
            acc[1][0] = mfma16(a1, bh0, acc[1][0]);
            acc[1][1] = mfma16(a1, bl1, acc[1][1]);
            acc[1][1] = mfma16(a1, bh1, acc[1][1]);
        }
        // epilogue: Z -> Zlh/Zll[x][p*16+ky] (hi + residual-lo)
#pragma unroll
        for (int mt = 0; mt < 2; ++mt)
#pragma unroll
            for (int nt = 0; nt < 2; ++nt)
#pragma unroll
                for (int r = 0; r < 4; ++r) {
                    float z = acc[mt][nt][r];
                    unsigned short zh = f2bf(z);
                    int idx = (32 * w + mt * 16 + q * 4 + r) * 40 + nt * 16 + lid;
                    Zlh[idx] = zh;
                    Zll[idx] = f2bf(z - bf2f(zh));
                }
        __syncthreads();

        // I2: out[x][y] = sum_k (Zh+Zl)[x][k] E4t[y][k];  M=128 N=128 K=32
        f32x4 acc2[2][8];
#pragma unroll
        for (int mt = 0; mt < 2; ++mt) {
            bf16x8 ah = *(const bf16x8*)&Zlh[(32 * w + mt * 16 + lid) * 40 + q * 8];
            bf16x8 al = *(const bf16x8*)&Zll[(32 * w + mt * 16 + lid) * 40 + q * 8];
#pragma unroll
            for (int nt = 0; nt < 8; ++nt) {
                bf16x8 bb = *(const bf16x8*)&tab[TAB_E4 + (nt * 16 + lid) * 32 + q * 8];
                f32x4 z = {};
                z = mfma16(al, bb, z);
                acc2[mt][nt] = mfma16(ah, bb, z);
            }
        }
        float* og = out + (size_t)(b * 32 + o0 + oo) * 16384;
#pragma unroll
        for (int mt = 0; mt < 2; ++mt)
#pragma unroll
            for (int r = 0; r < 4; ++r)
#pragma unroll
                for (int nt = 0; nt < 8; ++nt)
                    og[(32 * w + mt * 16 + q * 4 + r) * 128 + nt * 16 + lid] = acc2[mt][nt][r];
    }
}

extern "C" void kernel_launch(void* const* d_in, const int* in_sizes, int n_in,
                              void* d_out, int out_size, void* d_ws, size_t ws_size,
                              hipStream_t stream) {
    const float* x  = (const float*)d_in[0];
    const float* wr = (const float*)d_in[1];
    const float* wi = (const float*)d_in[2];
    float* out = (float*)d_out;
    float* ws  = (float*)d_ws;
    k_f <<<dim3(1024), dim3(256), 0, stream>>>(x, ws);
    k_im<<<dim3(512),  dim3(256), 0, stream>>>(ws, wr, wi, out);
}

// Round 6
// 133.809 us; speedup vs baseline: 1.0107x; 1.0107x over previous
//
#include <hip/hip_runtime.h>

#define PI_D 3.14159265358979323846

typedef __attribute__((ext_vector_type(8))) short bf16x8;
typedef __attribute__((ext_vector_type(4))) float f32x4;

static __device__ inline f32x4 mfma16(bf16x8 a, bf16x8 b, f32x4 c) {
    return __builtin_amdgcn_mfma_f32_16x16x32_bf16(a, b, c, 0, 0, 0);
}

// f32 -> bf16 RNE via native __bf16 cast (clang emits v_cvt_pk_bf16_f32 for pairs;
// bit-identical to integer RNE for finite values).
static __device__ inline unsigned short f2bf(float f) {
    union { __bf16 h; unsigned short u; } v;
    v.h = (__bf16)f;
    return v.u;
}
static __device__ inline float bf2f(unsigned short h) {
    union { unsigned u; float f; } v; v.u = ((unsigned)h) << 16;
    return v.f;
}

// load 8 consecutive f32 from global, convert to bf16x8
static __device__ inline bf16x8 ld_cvt8(const float* __restrict__ p) {
    float4 v0 = *(const float4*)p;
    float4 v1 = *(const float4*)(p + 4);
    bf16x8 r;
    r[0] = (short)f2bf(v0.x); r[1] = (short)f2bf(v0.y);
    r[2] = (short)f2bf(v0.z); r[3] = (short)f2bf(v0.w);
    r[4] = (short)f2bf(v1.x); r[5] = (short)f2bf(v1.y);
    r[6] = (short)f2bf(v1.z); r[7] = (short)f2bf(v1.w);
    return r;
}

// ---- ws float layout ----------------------------------------------------------------
#define OFF_TAB 0                         // 32768 bf16 = 16384 floats (only A3/E4 used)
#define OFF_WT3  16384                    // wt3[o*32+i][mode] cplx: 1024*512 float2
#define OFF_XFR  (16384 + 1048576)        // 1024 bids x 512 modes f32 (re)
#define OFF_XFI  (OFF_XFR + 524288)       // (im)

// table offsets in u16 units within OFF_TAB
#define TAB_A3 20480    // [128 x][64 k=c*32+m]
#define TAB_E4 28672    // [128 y][32 k=p*16+ky]

// ---------------- forward + all prep: kernel 1 ----------------------------------------
// Per block (b,i): forward transform of one image. bf16 twiddle tables from 128 angles;
// E1 staged as 8KB LDS fragment table; A2 thread-unique from bc/bs.
// Side duties: w3 relayout (all blocks), A3/E4 global tables (blocks 0/1).
__global__ __launch_bounds__(256) void k_f(const float* __restrict__ x,
                                           const float* __restrict__ wr,
                                           const float* __restrict__ wi,
                                           float* ws) {
    __shared__ float c128[128], s128[128];
    __shared__ unsigned short cb[128], sb[128], bc[128], bs[128];
    __shared__ __align__(16) unsigned short E1l[32 * 136];   // [n=c*16+ky][w]
    __shared__ __align__(16) unsigned short Yl[16 * 264];    // Y: [ky][k=c*128+x]
    int t = threadIdx.x, bid = blockIdx.x;
    const float W128 = (float)(2.0 * PI_D / 128.0);
    const float inv128 = 1.f / 128.f;
    if (t < 128) {
        float th = t * W128, c = cosf(th), s = sinf(th);
        c128[t] = c; s128[t] = s;
        cb[t] = f2bf(c * inv128);
        sb[t] = f2bf(-s * inv128);
        bc[t] = f2bf(c);
        bs[t] = f2bf(s);
    }

    // side duty (no LDS dep): w3 relayout, chunk bid = o*32+i
    {
        int o = bid >> 5, i = bid & 31;
        const float* r  = wr + (size_t)(i * 32 + o) * 512;
        const float* im = wi + (size_t)(i * 32 + o) * 512;
        float2* dst = (float2*)(ws + OFF_WT3) + (size_t)bid * 512;
        dst[t]       = make_float2(r[t],       im[t]);
        dst[t + 256] = make_float2(r[t + 256], im[t + 256]);
    }
    __syncthreads();

    // build E1l fragment table from cb/sb (each entry reused by 4 waves)
    for (int e = t; e < 4096; e += 256) {
        int row = e >> 7, col = e & 127;
        int ky = row & 15, c = row >> 4;
        int a = (col * ky) & 127;
        E1l[row * 136 + col] = c ? sb[a] : cb[a];
    }

    // side duty: blocks 0/1 emit the inverse-DFT tables for k_im (bit-identical math)
    unsigned short* tabw = (unsigned short*)(ws + OFF_TAB);
    if (bid == 0) {
        for (int idx = t; idx < 8192; idx += 256) {          // A3: inverse x-DFT
            int xx = idx >> 6, k = idx & 63, c = k >> 5, m = k & 31;
            int kx = (m < 16) ? m : 96 + m;
            int a = (xx * kx) & 127;
            float val = (c == 0) ? c128[a] : -s128[a];
            tabw[TAB_A3 + idx] = f2bf(val);
        }
    } else if (bid == 1) {
        for (int idx = t; idx < 4096; idx += 256) {          // E4t: inverse y-DFT
            int y = idx >> 5, k = idx & 31, p = k >> 4, ky = k & 15;
            int a = (y * ky) & 127;
            float sc = (ky == 0 ? 1.f : 2.f) / 128.f;
            float val = (p == 0) ? sc * c128[a] : -sc * s128[a];
            tabw[TAB_E4 + idx] = f2bf(val);
        }
    }
    __syncthreads();

    int lid = t & 15, q = (t >> 4) & 3, w = t >> 6;
    const float* xim = x + (size_t)bid * 16384;

    // F1: C[x][(c,ky)] = sum_w X[x][w] E1t[(c,ky)][w];  M=128 N=32 K=128
    f32x4 acc[2][2] = {};
#pragma unroll
    for (int ks = 0; ks < 4; ++ks) {
        bf16x8 a0 = ld_cvt8(xim + (32 * w + lid) * 128 + ks * 32 + q * 8);
        bf16x8 a1 = ld_cvt8(xim + (32 * w + 16 + lid) * 128 + ks * 32 + q * 8);
        bf16x8 b0 = *(const bf16x8*)&E1l[lid * 136 + ks * 32 + q * 8];
        bf16x8 b1 = *(const bf16x8*)&E1l[(16 + lid) * 136 + ks * 32 + q * 8];
        acc[0][0] = mfma16(a0, b0, acc[0][0]);
        acc[0][1] = mfma16(a0, b1, acc[0][1]);
        acc[1][0] = mfma16(a1, b0, acc[1][0]);
        acc[1][1] = mfma16(a1, b1, acc[1][1]);
    }
    // epilogue: Y -> Yl[ky][c*128+x] bf16
#pragma unroll
    for (int mt = 0; mt < 2; ++mt)
#pragma unroll
        for (int nt = 0; nt < 2; ++nt) {
            ushort4 h;
            h.x = f2bf(acc[mt][nt][0]); h.y = f2bf(acc[mt][nt][1]);
            h.z = f2bf(acc[mt][nt][2]); h.w = f2bf(acc[mt][nt][3]);
            *(ushort4*)&Yl[lid * 264 + nt * 128 + 32 * w + mt * 16 + q * 4] = h;
        }
    __syncthreads();

    // F2: C[(p,m)][ky] = sum_k A2[(p,m)][k] Yl[ky][k];  M=64 N=16 K=256
    f32x4 acc2 = {};
    {
        int row = 16 * w + lid, p = row >> 5, m = row & 31;
        int kx = (m < 16) ? m : 96 + m;
#pragma unroll
        for (int ks = 0; ks < 8; ++ks) {
            const bool cc = (ks >= 4);         // c = k>>7, compile-time per ks
            bf16x8 a;
#pragma unroll
            for (int j = 0; j < 8; ++j) {
                int xx = (ks * 32 + q * 8 + j) & 127;
                int ang = (xx * kx) & 127;
                unsigned short v;
                if (p == 0) v = cc ? bs[ang] : bc[ang];                      // er / -ei
                else        v = cc ? bc[ang] : (unsigned short)(bs[ang] ^ 0x8000u); // er / ei
                a[j] = (short)v;
            }
            bf16x8 b = *(const bf16x8*)&Yl[lid * 264 + ks * 32 + q * 8];
            acc2 = mfma16(a, b, acc2);
        }
    }
    int p = w >> 1, mb = (w & 1) * 16;
    float* xfp = ws + (p ? OFF_XFI : OFF_XFR) + (size_t)bid * 512;
#pragma unroll
    for (int r = 0; r < 4; ++r)
        xfp[(mb + q * 4 + r) * 16 + lid] = acc2[r];
}

// ---------------- fused mix + inverse: block (2b x 2o) -> 4 output images -------------
// 2x2 register tiling: mix cache traffic = 134MB x (1/Bt + 1/Ot) = 134MB (R4's 1x4
// o-quad was 168MB). Grid 256, LDS 46KB, per-thread loads/iter unchanged (6).
// FMA order per output identical to before (bit-exact).
__global__ __launch_bounds__(256) void k_im(const float* __restrict__ ws, float* __restrict__ out) {
    __shared__ __align__(16) unsigned short Zlh[128 * 40];   // [x][k=p*16+ky] hi
    __shared__ __align__(16) unsigned short Zll[128 * 40];   // lo residual
    __shared__ __align__(16) unsigned short Blh[32 * 72];    // [(p,ky)][k=c*32+m] hi
    __shared__ __align__(16) unsigned short Bll[32 * 72];    // lo residual
    __shared__ float2 zm[4][512];
    int t = threadIdx.x, bid = blockIdx.x;                   // (b-pair)*16 + (o-pair)
    int b0 = (bid >> 4) * 2, o0 = (bid & 15) * 2;
    const unsigned short* tab = (const unsigned short*)(ws + OFF_TAB);

    // ---- channel mix, f32: zm[bb*2+oo][mode] = sum_i xf[b0+bb,i,mode] * w3[o0+oo,i,mode]
    {
        const float* xfr = ws + OFF_XFR + (size_t)(b0 * 32) * 512 + 2 * t;
        const float* xfi = ws + OFF_XFI + (size_t)(b0 * 32) * 512 + 2 * t;
        const float* w3  = ws + OFF_WT3 + ((size_t)(o0 * 32) * 512 + 2 * t) * 2;
        float ar[2][2][2] = {}, ai[2][2][2] = {};   // [bb][oo][mode01]
#pragma unroll 2
        for (int i = 0; i < 32; ++i) {
            float2 xr2[2], xi2[2];
#pragma unroll
            for (int bb = 0; bb < 2; ++bb) {
                xr2[bb] = *(const float2*)(xfr + (size_t)(bb * 32 + i) * 512);
                xi2[bb] = *(const float2*)(xfi + (size_t)(bb * 32 + i) * 512);
            }
#pragma unroll
            for (int oo = 0; oo < 2; ++oo) {
                const float4 w4 = *(const float4*)(w3 + (size_t)(oo * 32 + i) * 1024);
#pragma unroll
                for (int bb = 0; bb < 2; ++bb) {
                    ar[bb][oo][0] = fmaf(xr2[bb].x, w4.x, fmaf(-xi2[bb].x, w4.y, ar[bb][oo][0]));
                    ai[bb][oo][0] = fmaf(xr2[bb].x, w4.y, fmaf( xi2[bb].x, w4.x, ai[bb][oo][0]));
                    ar[bb][oo][1] = fmaf(xr2[bb].y, w4.z, fmaf(-xi2[bb].y, w4.w, ar[bb][oo][1]));
                    ai[bb][oo][1] = fmaf(xr2[bb].y, w4.w, fmaf( xi2[bb].y, w4.z, ai[bb][oo][1]));
                }
            }
        }
#pragma unroll
        for (int bb = 0; bb < 2; ++bb)
#pragma unroll
            for (int oo = 0; oo < 2; ++oo) {
                zm[bb * 2 + oo][2 * t]     = make_float2(ar[bb][oo][0], ai[bb][oo][0]);
                zm[bb * 2 + oo][2 * t + 1] = make_float2(ar[bb][oo][1], ai[bb][oo][1]);
            }
    }

    int lid = t & 15, q = (t >> 4) & 3, w = t >> 6;

    for (int img = 0; img < 4; ++img) {
        int bb = img >> 1, oo = img & 1;
        __syncthreads();   // zm ready / previous I1-read of Blh done

        // build Blh/Bll from zm[img] (complex-as-real with sign trick; hi + residual-lo)
        {
            int n = t >> 3, k0 = (t & 7) * 8;
            int p = n >> 4, ky = n & 15;
            unsigned short hh[8], hl[8];
#pragma unroll
            for (int j = 0; j < 8; ++j) {
                int k = k0 + j, c = k >> 5, m = k & 31;
                float2 v = zm[img][m * 16 + ky];
                float val = (p == 0) ? (c == 0 ? v.x : v.y) : (c == 0 ? v.y : -v.x);
                unsigned short vh = f2bf(val);
                hh[j] = vh;
                hl[j] = f2bf(val - bf2f(vh));
            }
            ushort4 a, bb2;
            a.x = hh[0]; a.y = hh[1]; a.z = hh[2]; a.w = hh[3];
            bb2.x = hh[4]; bb2.y = hh[5]; bb2.z = hh[6]; bb2.w = hh[7];
            *(ushort4*)&Blh[n * 72 + k0]     = a;
            *(ushort4*)&Blh[n * 72 + k0 + 4] = bb2;
            a.x = hl[0]; a.y = hl[1]; a.z = hl[2]; a.w = hl[3];
            bb2.x = hl[4]; bb2.y = hl[5]; bb2.z = hl[6]; bb2.w = hl[7];
            *(ushort4*)&Bll[n * 72 + k0]     = a;
            *(ushort4*)&Bll[n * 72 + k0 + 4] = bb2;
        }
        __syncthreads();

        // I1: Z[x][(p,ky)] = sum_k A3[x][k] (Bh+Bl)[(p,ky)][k];  M=128 N=32 K=64
        f32x4 acc[2][2] = {};
#pragma unroll
        for (int ks = 0; ks < 2; ++ks) {
            bf16x8 a0  = *(const bf16x8*)&tab[TAB_A3 + (32 * w + lid) * 64 + ks * 32 + q * 8];
            bf16x8 a1  = *(const bf16x8*)&tab[TAB_A3 + (32 * w + 16 + lid) * 64 + ks * 32 + q * 8];
            bf16x8 bh0 = *(const bf16x8*)&Blh[lid * 72 + ks * 32 + q * 8];
            bf16x8 bh1 = *(const bf16x8*)&Blh[(16 + lid) * 72 + ks * 32 + q * 8];
            bf16x8 bl0 = *(const bf16x8*)&Bll[lid * 72 + ks * 32 + q * 8];
            bf16x8 bl1 = *(const bf16x8*)&Bll[(16 + lid) * 72 + ks * 32 + q * 8];
            acc[0][0] = mfma16(a0, bl0, acc[0][0]);
            acc[0][0] = mfma16(a0, bh0, acc[0][0]);
            acc[0][1] = mfma16(a0, bl1, acc[0][1]);
            acc[0][1] = mfma16(a0, bh1, acc[0][1]);
            acc[1][0] = mfma16(a1, bl0, acc[1][0]);
            acc[1][0] = mfma16(a1, bh0, acc[1][0]);
            acc[1][1] = mfma16(a1, bl1, acc[1][1]);
            acc[1][1] = mfma16(a1, bh1, acc[1][1]);
        }
        // epilogue: Z -> Zlh/Zll[x][p*16+ky] (hi + residual-lo)
#pragma unroll
        for (int mt = 0; mt < 2; ++mt)
#pragma unroll
            for (int nt = 0; nt < 2; ++nt)
#pragma unroll
                for (int r = 0; r < 4; ++r) {
                    float z = acc[mt][nt][r];
                    unsigned short zh = f2bf(z);
                    int idx = (32 * w + mt * 16 + q * 4 + r) * 40 + nt * 16 + lid;
                    Zlh[idx] = zh;
                    Zll[idx] = f2bf(z - bf2f(zh));
                }
        __syncthreads();

        // I2: out[x][y] = sum_k (Zh+Zl)[x][k] E4t[y][k];  M=128 N=128 K=32
        f32x4 acc2[2][8];
#pragma unroll
        for (int mt = 0; mt < 2; ++mt) {
            bf16x8 ah = *(const bf16x8*)&Zlh[(32 * w + mt * 16 + lid) * 40 + q * 8];
            bf16x8 al = *(const bf16x8*)&Zll[(32 * w + mt * 16 + lid) * 40 + q * 8];
#pragma unroll
            for (int nt = 0; nt < 8; ++nt) {
                bf16x8 bb2 = *(const bf16x8*)&tab[TAB_E4 + (nt * 16 + lid) * 32 + q * 8];
                f32x4 z = {};
                z = mfma16(al, bb2, z);
                acc2[mt][nt] = mfma16(ah, bb2, z);
            }
        }
        float* og = out + (size_t)((b0 + bb) * 32 + o0 + oo) * 16384;
#pragma unroll
        for (int mt = 0; mt < 2; ++mt)
#pragma unroll
            for (int r = 0; r < 4; ++r)
#pragma unroll
                for (int nt = 0; nt < 8; ++nt)
                    og[(32 * w + mt * 16 + q * 4 + r) * 128 + nt * 16 + lid] = acc2[mt][nt][r];
    }
}

extern "C" void kernel_launch(void* const* d_in, const int* in_sizes, int n_in,
                              void* d_out, int out_size, void* d_ws, size_t ws_size,
                              hipStream_t stream) {
    const float* x  = (const float*)d_in[0];
    const float* wr = (const float*)d_in[1];
    const float* wi = (const float*)d_in[2];
    float* out = (float*)d_out;
    float* ws  = (float*)d_ws;
    k_f <<<dim3(1024), dim3(256), 0, stream>>>(x, wr, wi, ws);
    k_im<<<dim3(256),  dim3(256), 0, stream>>>(ws, out);
}